// Round 1
// 694.455 us; speedup vs baseline: 1.1617x; 1.1617x over previous
//
#include <hip/hip_runtime.h>
#include <math.h>

#define NNODES 50000
#define NEDGES 800000
#define INC 512
#define OUTC 256
#define DECD 256
#define NMASK 25000

#define SCAN_B 1024
#define NSCAN ((NNODES + SCAN_B - 1) / SCAN_B)   // 49 blocks

typedef __attribute__((ext_vector_type(8))) short short8;
typedef __attribute__((ext_vector_type(4))) float f32x4;

__device__ __forceinline__ unsigned short f2bf(float f) {
    unsigned int u = __float_as_uint(f);
    u = (u + 0x7fff + ((u >> 16) & 1)) >> 16;   // RNE
    return (unsigned short)u;
}
__device__ __forceinline__ float bf2f(unsigned short u) {
    return __uint_as_float(((unsigned int)u) << 16);
}

// ---------------- degree / CSR construction ----------------

__global__ void count_deg_k(const int* __restrict__ dst, int* __restrict__ deg) {
    int e = blockIdx.x * blockDim.x + threadIdx.x;
    if (e < NEDGES) atomicAdd(&deg[dst[e]], 1);
}

// Parallel scan, phase 1: per-block (1024-elem) sums; also emits dinv.
__global__ __launch_bounds__(1024) void scan_part_k(const int* __restrict__ deg,
                                                    int* __restrict__ bsum,
                                                    float* __restrict__ dinv) {
    int i = blockIdx.x * SCAN_B + threadIdx.x;
    int v = (i < NNODES) ? deg[i] : 0;
    if (i < NNODES) dinv[i] = rsqrtf((float)v + 1.0f);   // +1 self-loop
    int lane = threadIdx.x & 63, w = threadIdx.x >> 6;
    int s = v;
#pragma unroll
    for (int d = 32; d > 0; d >>= 1) s += __shfl_down(s, d, 64);
    __shared__ int ws[16];
    if (lane == 0) ws[w] = s;
    __syncthreads();
    if (threadIdx.x == 0) {
        int tot = 0;
#pragma unroll
        for (int j = 0; j < 16; ++j) tot += ws[j];
        bsum[blockIdx.x] = tot;
    }
}

// Phase 2: one wave scans the 49 block sums -> exclusive carries + total.
__global__ __launch_bounds__(64) void scan_carry_k(const int* __restrict__ bsum,
                                                   int* __restrict__ bcarry,
                                                   int* __restrict__ offs) {
    int t = threadIdx.x;
    int v = (t < NSCAN) ? bsum[t] : 0;
    int incl = v;
#pragma unroll
    for (int d = 1; d < 64; d <<= 1) {
        int u = __shfl_up(incl, d, 64);
        if (t >= d) incl += u;
    }
    if (t < NSCAN) bcarry[t] = incl - v;
    if (t == 63) offs[NNODES] = incl;   // grand total (= NEDGES)
}

// Phase 3: per-block exclusive scan + carry -> offs, cursor.
__global__ __launch_bounds__(1024) void scan_fin_k(const int* __restrict__ deg,
                                                   const int* __restrict__ bcarry,
                                                   int* __restrict__ offs,
                                                   int* __restrict__ cursor) {
    int i = blockIdx.x * SCAN_B + threadIdx.x;
    int v = (i < NNODES) ? deg[i] : 0;
    int lane = threadIdx.x & 63, w = threadIdx.x >> 6;
    int incl = v;
#pragma unroll
    for (int d = 1; d < 64; d <<= 1) {
        int u = __shfl_up(incl, d, 64);
        if (lane >= d) incl += u;
    }
    __shared__ int ws[16];
    if (lane == 63) ws[w] = incl;
    __syncthreads();
    int carry = bcarry[blockIdx.x];
    for (int j = 0; j < w; ++j) carry += ws[j];
    int ex = carry + incl - v;
    if (i < NNODES) { offs[i] = ex; cursor[i] = ex; }
}

// CSR fill: one 8B record per edge (src, coef) -> halves scatter line traffic.
__global__ void fill_csr_k(const int* __restrict__ src, const int* __restrict__ dst,
                           const float* __restrict__ dinv, int* __restrict__ cursor,
                           int2* __restrict__ edges) {
    int e = blockIdx.x * blockDim.x + threadIdx.x;
    if (e >= NEDGES) return;
    int s = src[e], d = dst[e];
    int pos = atomicAdd(&cursor[d], 1);
    edges[pos] = make_int2(s, __float_as_int(dinv[s] * dinv[d]));
}

// ---------------- conversions ----------------

// one pass over x: out_x (fp32 copy) + x_bf (bf16)
__global__ void cvt_copy_k(const float4* __restrict__ in, float4* __restrict__ outx,
                           ushort4* __restrict__ outbf, int n4) {
    int i = blockIdx.x * blockDim.x + threadIdx.x;
    if (i >= n4) return;
    float4 v = in[i];
    outx[i] = v;
    ushort4 u;
    u.x = f2bf(v.x); u.y = f2bf(v.y); u.z = f2bf(v.z); u.w = f2bf(v.w);
    outbf[i] = u;
}

// W[K][N] f32 -> Wt[N][K] bf16 (coalesced writes)
__global__ void wt_k(const float* __restrict__ W, unsigned short* __restrict__ Wt,
                     int K, int N) {
    int o = blockIdx.x * blockDim.x + threadIdx.x;
    if (o >= K * N) return;
    int n = o / K;
    int k = o - n * K;
    Wt[o] = f2bf(W[(size_t)k * N + n]);
}

// token_h[j] = sum_k mask_token[k] * enc_W[k][j]  (fp32)
__global__ void token_k(const float* __restrict__ token, const float* __restrict__ W,
                        float* __restrict__ outv) {
    int j = threadIdx.x;
    float s = 0.f;
    for (int k = 0; k < INC; ++k) s += token[k] * W[(size_t)k * OUTC + j];
    outv[j] = s;
}

// overwrite masked rows of h1(bf16) with token_h
__global__ __launch_bounds__(64) void maskfix_bf_k(const int* __restrict__ idx,
                                                   const float* __restrict__ tokh,
                                                   unsigned short* __restrict__ h1) {
    int r = idx[blockIdx.x];
    int t = threadIdx.x;
    float4 v = *(const float4*)(tokh + t * 4);
    ushort4 u;
    u.x = f2bf(v.x); u.y = f2bf(v.y); u.z = f2bf(v.z); u.w = f2bf(v.w);
    *(ushort4*)(h1 + (size_t)r * OUTC + t * 4) = u;
}

__global__ void maskout_k(const int* __restrict__ idx, float* __restrict__ out) {
    int i = blockIdx.x * blockDim.x + threadIdx.x;
    if (i < NMASK) out[i] = (float)idx[i];
}

// ---------------- bf16 MFMA GEMM ----------------
// C[M,N] = A[M,K](bf16) @ Bt[N,K](bf16)^T  (+bias), C fp32 or bf16.
// 128x128 tile, BK=32, 256 threads = 4 waves (2x2 of 64x64), 16x16x32 MFMA.
// Staging via global_load_lds width=16 into unpadded [128][32] bf16 LDS tiles.

__global__ __launch_bounds__(256) void gemm_bf16_k(const unsigned short* __restrict__ A,
                                                   const unsigned short* __restrict__ Bt,
                                                   void* __restrict__ Cout,
                                                   int M, int K, int N,
                                                   const float* __restrict__ bias,
                                                   int out_bf16) {
    __shared__ unsigned short As[128 * 32];   // 8 KB
    __shared__ unsigned short Bs[128 * 32];   // 8 KB
    const int t = threadIdx.x;
    const int lane = t & 63, wv = t >> 6;
    const int bm = blockIdx.y * 128;
    const int bn = blockIdx.x * 128;
    const int wm = (wv >> 1) * 64, wn = (wv & 1) * 64;
    const int lr = lane & 15, lq = lane >> 4;

    f32x4 acc[4][4] = {};

    for (int k0 = 0; k0 < K; k0 += 32) {
        __syncthreads();
#pragma unroll
        for (int r = 0; r < 2; ++r) {
            int idx = r * 256 + wv * 64 + lane;   // 0..511
            int row = idx >> 2;                   // 0..127
            int c8 = (idx & 3) * 8;               // 0,8,16,24
            int ga = bm + row;
            if (ga >= M) ga = M - 1;              // clamp tail (stores guarded)
            const unsigned short* gA = A + (size_t)ga * K + k0 + c8;
            const unsigned short* gB = Bt + (size_t)(bn + row) * K + k0 + c8;
            __builtin_amdgcn_global_load_lds(
                (const __attribute__((address_space(1))) unsigned int*)gA,
                (__attribute__((address_space(3))) unsigned int*)&As[(r * 256 + wv * 64) * 8],
                16, 0, 0);
            __builtin_amdgcn_global_load_lds(
                (const __attribute__((address_space(1))) unsigned int*)gB,
                (__attribute__((address_space(3))) unsigned int*)&Bs[(r * 256 + wv * 64) * 8],
                16, 0, 0);
        }
        __syncthreads();

        short8 av[4], bv[4];
#pragma unroll
        for (int mt = 0; mt < 4; ++mt)
            av[mt] = *(const short8*)&As[(wm + mt * 16 + lr) * 32 + lq * 8];
#pragma unroll
        for (int nt = 0; nt < 4; ++nt)
            bv[nt] = *(const short8*)&Bs[(wn + nt * 16 + lr) * 32 + lq * 8];
#pragma unroll
        for (int mt = 0; mt < 4; ++mt)
#pragma unroll
            for (int nt = 0; nt < 4; ++nt)
                acc[mt][nt] = __builtin_amdgcn_mfma_f32_16x16x32_bf16(
                    av[mt], bv[nt], acc[mt][nt], 0, 0, 0);
    }

    // epilogue: D[row][col], col = lane&15, row = (lane>>4)*4 + reg
    float* Cf = (float*)Cout;
    unsigned short* Cb = (unsigned short*)Cout;
#pragma unroll
    for (int nt = 0; nt < 4; ++nt) {
        int col = bn + wn + nt * 16 + lr;
        float bv_ = bias ? bias[col] : 0.f;
#pragma unroll
        for (int mt = 0; mt < 4; ++mt) {
            int row0 = bm + wm + mt * 16 + lq * 4;
#pragma unroll
            for (int reg = 0; reg < 4; ++reg) {
                int row = row0 + reg;
                if (row >= M) continue;
                float v = acc[mt][nt][reg] + bv_;
                if (out_bf16) Cb[(size_t)row * N + col] = f2bf(v);
                else          Cf[(size_t)row * N + col] = v;
            }
        }
    }
}

// ---------------- GCN aggregation (bf16 in/out, fp32 accum) ----------------

__global__ __launch_bounds__(64) void agg_bf_k(const unsigned short* __restrict__ h,
                                               unsigned short* __restrict__ out,
                                               const float* __restrict__ bias,
                                               const float* __restrict__ dinv,
                                               const int* __restrict__ offs,
                                               const int2* __restrict__ edges,
                                               int do_relu) {
    int node = blockIdx.x;
    int t = threadIdx.x;                 // 64 threads x 4 ch = 256 channels
    int beg = offs[node], end = offs[node + 1];
    float a0 = 0.f, a1 = 0.f, a2 = 0.f, a3 = 0.f;
    for (int e = beg; e < end; ++e) {
        int2 ev = edges[e];
        int s = ev.x;
        float c = __int_as_float(ev.y);
        ushort4 v = *(const ushort4*)(h + (size_t)s * OUTC + t * 4);
        a0 += bf2f(v.x) * c; a1 += bf2f(v.y) * c;
        a2 += bf2f(v.z) * c; a3 += bf2f(v.w) * c;
    }
    float di = dinv[node];
    float sc = di * di;
    ushort4 hv = *(const ushort4*)(h + (size_t)node * OUTC + t * 4);
    float4 bv = *(const float4*)(bias + t * 4);
    a0 += bf2f(hv.x) * sc + bv.x;
    a1 += bf2f(hv.y) * sc + bv.y;
    a2 += bf2f(hv.z) * sc + bv.z;
    a3 += bf2f(hv.w) * sc + bv.w;
    if (do_relu) {
        a0 = fmaxf(a0, 0.f); a1 = fmaxf(a1, 0.f);
        a2 = fmaxf(a2, 0.f); a3 = fmaxf(a3, 0.f);
    }
    ushort4 u;
    u.x = f2bf(a0); u.y = f2bf(a1); u.z = f2bf(a2); u.w = f2bf(a3);
    *(ushort4*)(out + (size_t)node * OUTC + t * 4) = u;
}

// ---------------- launch ----------------

extern "C" void kernel_launch(void* const* d_in, const int* in_sizes, int n_in,
                              void* d_out, int out_size, void* d_ws, size_t ws_size,
                              hipStream_t stream) {
    const float* x    = (const float*)d_in[0];
    const int*   eidx = (const int*)d_in[1];
    const int*   midx = (const int*)d_in[2];
    const float* mtok = (const float*)d_in[3];
    const float* encW = (const float*)d_in[4];
    const float* encB = (const float*)d_in[5];
    const float* decW = (const float*)d_in[6];
    const float* decB = (const float*)d_in[7];
    const float* mlpW = (const float*)d_in[8];
    const float* mlpB = (const float*)d_in[9];
    const int* srcs = eidx;
    const int* dsts = eidx + NEDGES;

    char* ws = (char*)d_ws;
    unsigned short* x_bf  = (unsigned short*)(ws + 0);            // 51,200,000
    unsigned short* hA_bf = (unsigned short*)(ws + 51200000);     // 25,600,000 (GEMM outs)
    unsigned short* hB_bf = (unsigned short*)(ws + 76800000);     // 25,600,000 (agg outs)
    int*   deg    = (int*)  (ws + 102400000);
    float* dinv   = (float*)(ws + 102600000);
    int*   offs   = (int*)  (ws + 102800000);
    int*   cursor = (int*)  (ws + 103000064);
    int2*  edges  = (int2*) (ws + 103200064);    // 6,400,000
    float* tokh   = (float*)(ws + 109600064);    // 1,024
    unsigned short* encWt = (unsigned short*)(ws + 109601088);    // 262,144
    unsigned short* decWt = (unsigned short*)(ws + 109863232);    // 131,072
    unsigned short* mlpWt = (unsigned short*)(ws + 109994304);    // 262,144
    int*   bsum   = (int*)  (ws + 110256448);    // 256
    int*   bcarry = (int*)  (ws + 110256704);    // 256

    float* out_recon = (float*)d_out;
    float* out_x     = out_recon + (size_t)NNODES * INC;
    float* out_mask  = out_x + (size_t)NNODES * INC;

    hipMemsetAsync(deg, 0, NNODES * sizeof(int), stream);
    count_deg_k<<<(NEDGES + 255) / 256, 256, 0, stream>>>(dsts, deg);
    scan_part_k<<<NSCAN, SCAN_B, 0, stream>>>(deg, bsum, dinv);
    scan_carry_k<<<1, 64, 0, stream>>>(bsum, bcarry, offs);
    scan_fin_k<<<NSCAN, SCAN_B, 0, stream>>>(deg, bcarry, offs, cursor);
    fill_csr_k<<<(NEDGES + 255) / 256, 256, 0, stream>>>(srcs, dsts, dinv, cursor, edges);

    token_k<<<1, 256, 0, stream>>>(mtok, encW, tokh);

    // conversions (x read once: out_x copy + bf16 cast)
    cvt_copy_k<<<(NNODES * INC / 4 + 255) / 256, 256, 0, stream>>>(
        (const float4*)x, (float4*)out_x, (ushort4*)x_bf, NNODES * INC / 4);
    wt_k<<<(INC * OUTC + 255) / 256, 256, 0, stream>>>(encW, encWt, INC, OUTC);
    wt_k<<<(OUTC * DECD + 255) / 256, 256, 0, stream>>>(decW, decWt, OUTC, DECD);
    wt_k<<<(DECD * INC + 255) / 256, 256, 0, stream>>>(mlpW, mlpWt, DECD, INC);

    // encoder GEMM: h1 = x @ enc_W  (bf16 out), then mask fixup
    gemm_bf16_k<<<dim3(OUTC / 128, (NNODES + 127) / 128), 256, 0, stream>>>(
        x_bf, encWt, hA_bf, NNODES, INC, OUTC, nullptr, 1);
    maskfix_bf_k<<<NMASK, 64, 0, stream>>>(midx, tokh, hA_bf);

    // z = agg(h1) + h1*dinv^2 + enc_b  (bf16 out)
    agg_bf_k<<<NNODES, 64, 0, stream>>>(hA_bf, hB_bf, encB, dinv, offs, edges, 0);

    // decoder GEMM: h2 = z @ dec_W (bf16 out)
    gemm_bf16_k<<<dim3(DECD / 128, (NNODES + 127) / 128), 256, 0, stream>>>(
        hB_bf, decWt, hA_bf, NNODES, OUTC, DECD, nullptr, 1);

    // h = relu(agg(h2) + h2*dinv^2 + dec_b) (bf16 out)
    agg_bf_k<<<NNODES, 64, 0, stream>>>(hA_bf, hB_bf, decB, dinv, offs, edges, 1);

    // x_recon = h @ mlp_W + mlp_b -> fp32 directly to d_out
    gemm_bf16_k<<<dim3(INC / 128, (NNODES + 127) / 128), 256, 0, stream>>>(
        hB_bf, mlpWt, out_recon, NNODES, DECD, INC, mlpB, 0);

    // output 3: mask indices as fp32
    maskout_k<<<(NMASK + 255) / 256, 256, 0, stream>>>(midx, out_mask);
}

// Round 2
// 673.006 us; speedup vs baseline: 1.1987x; 1.0319x over previous
//
#include <hip/hip_runtime.h>
#include <math.h>

#define NNODES 50000
#define NEDGES 800000
#define INC 512
#define OUTC 256
#define DECD 256
#define NMASK 25000

#define SCAN_B 1024
#define NSCAN ((NNODES + SCAN_B - 1) / SCAN_B)   // 49 blocks

typedef __attribute__((ext_vector_type(8))) short short8;
typedef __attribute__((ext_vector_type(4))) float f32x4;

__device__ __forceinline__ unsigned short f2bf(float f) {
    unsigned int u = __float_as_uint(f);
    u = (u + 0x7fff + ((u >> 16) & 1)) >> 16;   // RNE
    return (unsigned short)u;
}
__device__ __forceinline__ float bf2f(unsigned short u) {
    return __uint_as_float(((unsigned int)u) << 16);
}

// ---------------- degree / CSR construction ----------------

__global__ void count_deg_k(const int* __restrict__ dst, int* __restrict__ deg) {
    int e = blockIdx.x * blockDim.x + threadIdx.x;
    if (e < NEDGES) atomicAdd(&deg[dst[e]], 1);
}

// Parallel scan, phase 1: per-block (1024-elem) sums; also emits dinv.
__global__ __launch_bounds__(1024) void scan_part_k(const int* __restrict__ deg,
                                                    int* __restrict__ bsum,
                                                    float* __restrict__ dinv) {
    int i = blockIdx.x * SCAN_B + threadIdx.x;
    int v = (i < NNODES) ? deg[i] : 0;
    if (i < NNODES) dinv[i] = rsqrtf((float)v + 1.0f);   // +1 self-loop
    int lane = threadIdx.x & 63, w = threadIdx.x >> 6;
    int s = v;
#pragma unroll
    for (int d = 32; d > 0; d >>= 1) s += __shfl_down(s, d, 64);
    __shared__ int ws[16];
    if (lane == 0) ws[w] = s;
    __syncthreads();
    if (threadIdx.x == 0) {
        int tot = 0;
#pragma unroll
        for (int j = 0; j < 16; ++j) tot += ws[j];
        bsum[blockIdx.x] = tot;
    }
}

// Phase 2: one wave scans the 49 block sums -> exclusive carries + total.
__global__ __launch_bounds__(64) void scan_carry_k(const int* __restrict__ bsum,
                                                   int* __restrict__ bcarry,
                                                   int* __restrict__ offs) {
    int t = threadIdx.x;
    int v = (t < NSCAN) ? bsum[t] : 0;
    int incl = v;
#pragma unroll
    for (int d = 1; d < 64; d <<= 1) {
        int u = __shfl_up(incl, d, 64);
        if (t >= d) incl += u;
    }
    if (t < NSCAN) bcarry[t] = incl - v;
    if (t == 63) offs[NNODES] = incl;   // grand total (= NEDGES)
}

// Phase 3: per-block exclusive scan + carry -> offs, cursor.
__global__ __launch_bounds__(1024) void scan_fin_k(const int* __restrict__ deg,
                                                   const int* __restrict__ bcarry,
                                                   int* __restrict__ offs,
                                                   int* __restrict__ cursor) {
    int i = blockIdx.x * SCAN_B + threadIdx.x;
    int v = (i < NNODES) ? deg[i] : 0;
    int lane = threadIdx.x & 63, w = threadIdx.x >> 6;
    int incl = v;
#pragma unroll
    for (int d = 1; d < 64; d <<= 1) {
        int u = __shfl_up(incl, d, 64);
        if (lane >= d) incl += u;
    }
    __shared__ int ws[16];
    if (lane == 63) ws[w] = incl;
    __syncthreads();
    int carry = bcarry[blockIdx.x];
    for (int j = 0; j < w; ++j) carry += ws[j];
    int ex = carry + incl - v;
    if (i < NNODES) { offs[i] = ex; cursor[i] = ex; }
}

// CSR fill: one 8B record per edge (src, coef); also emits out_mask (fold).
__global__ void fill_csr_k(const int* __restrict__ src, const int* __restrict__ dst,
                           const float* __restrict__ dinv, int* __restrict__ cursor,
                           int2* __restrict__ edges,
                           const int* __restrict__ midx, float* __restrict__ out_mask) {
    int e = blockIdx.x * blockDim.x + threadIdx.x;
    if (e >= NEDGES) return;
    if (e < NMASK) out_mask[e] = (float)midx[e];
    int s = src[e], d = dst[e];
    int pos = atomicAdd(&cursor[d], 1);
    edges[pos] = make_int2(s, __float_as_int(dinv[s] * dinv[d]));
}

// ---------------- conversions ----------------

// one pass over x: out_x (fp32 copy) + x_bf (bf16)
__global__ void cvt_copy_k(const float4* __restrict__ in, float4* __restrict__ outx,
                           ushort4* __restrict__ outbf, int n4) {
    int i = blockIdx.x * blockDim.x + threadIdx.x;
    if (i >= n4) return;
    float4 v = in[i];
    outx[i] = v;
    ushort4 u;
    u.x = f2bf(v.x); u.y = f2bf(v.y); u.z = f2bf(v.z); u.w = f2bf(v.w);
    outbf[i] = u;
}

// all three weight transposes in one launch: Wt[n][k] = bf16(W[k][n])
__global__ void wt3_k(const float* __restrict__ encW, const float* __restrict__ decW,
                      const float* __restrict__ mlpW,
                      unsigned short* __restrict__ encWt, unsigned short* __restrict__ decWt,
                      unsigned short* __restrict__ mlpWt) {
    int o = blockIdx.x * blockDim.x + threadIdx.x;
    if (o < 131072) {                       // enc: N=256, K=512
        int n = o >> 9, k = o & 511;
        encWt[o] = f2bf(encW[(size_t)k * OUTC + n]);
    } else if (o < 131072 + 65536) {        // dec: N=256, K=256
        int o2 = o - 131072;
        int n = o2 >> 8, k = o2 & 255;
        decWt[o2] = f2bf(decW[(size_t)k * DECD + n]);
    } else if (o < 131072 + 65536 + 131072) {  // mlp: N=512, K=256
        int o2 = o - 131072 - 65536;
        int n = o2 >> 8, k = o2 & 255;
        mlpWt[o2] = f2bf(mlpW[(size_t)k * INC + n]);
    }
}

// token_h[j] = sum_k mask_token[k] * enc_W[k][j]  (parallel: 1 block per j)
__global__ __launch_bounds__(64) void token_k(const float* __restrict__ token,
                                              const float* __restrict__ W,
                                              float* __restrict__ outv) {
    int j = blockIdx.x;        // 0..255
    int l = threadIdx.x;       // 0..63
    float s = 0.f;
#pragma unroll
    for (int i = 0; i < INC / 64; ++i) {
        int k = i * 64 + l;
        s += token[k] * W[(size_t)k * OUTC + j];
    }
#pragma unroll
    for (int d = 32; d > 0; d >>= 1) s += __shfl_down(s, d, 64);
    if (l == 0) outv[j] = s;
}

// overwrite masked rows of h1(bf16) with token_h
__global__ __launch_bounds__(64) void maskfix_bf_k(const int* __restrict__ idx,
                                                   const float* __restrict__ tokh,
                                                   unsigned short* __restrict__ h1) {
    int r = idx[blockIdx.x];
    int t = threadIdx.x;
    float4 v = *(const float4*)(tokh + t * 4);
    ushort4 u;
    u.x = f2bf(v.x); u.y = f2bf(v.y); u.z = f2bf(v.z); u.w = f2bf(v.w);
    *(ushort4*)(h1 + (size_t)r * OUTC + t * 4) = u;
}

// ---------------- bf16 MFMA GEMM ----------------
// C[M,N] = A[M,K](bf16) @ Bt[N,K](bf16)^T  (+bias), C fp32 or bf16.
// 128x128 tile, BK=32, 256 threads = 4 waves (2x2 of 64x64), 16x16x32 MFMA.
// Staging via global_load_lds width=16 into unpadded [128][32] bf16 LDS tiles.

__global__ __launch_bounds__(256) void gemm_bf16_k(const unsigned short* __restrict__ A,
                                                   const unsigned short* __restrict__ Bt,
                                                   void* __restrict__ Cout,
                                                   int M, int K, int N,
                                                   const float* __restrict__ bias,
                                                   int out_bf16) {
    __shared__ unsigned short As[128 * 32];   // 8 KB
    __shared__ unsigned short Bs[128 * 32];   // 8 KB
    const int t = threadIdx.x;
    const int lane = t & 63, wv = t >> 6;
    const int bm = blockIdx.y * 128;
    const int bn = blockIdx.x * 128;
    const int wm = (wv >> 1) * 64, wn = (wv & 1) * 64;
    const int lr = lane & 15, lq = lane >> 4;

    f32x4 acc[4][4] = {};

    for (int k0 = 0; k0 < K; k0 += 32) {
        __syncthreads();
#pragma unroll
        for (int r = 0; r < 2; ++r) {
            int idx = r * 256 + wv * 64 + lane;   // 0..511
            int row = idx >> 2;                   // 0..127
            int c8 = (idx & 3) * 8;               // 0,8,16,24
            int ga = bm + row;
            if (ga >= M) ga = M - 1;              // clamp tail (stores guarded)
            const unsigned short* gA = A + (size_t)ga * K + k0 + c8;
            const unsigned short* gB = Bt + (size_t)(bn + row) * K + k0 + c8;
            __builtin_amdgcn_global_load_lds(
                (const __attribute__((address_space(1))) unsigned int*)gA,
                (__attribute__((address_space(3))) unsigned int*)&As[(r * 256 + wv * 64) * 8],
                16, 0, 0);
            __builtin_amdgcn_global_load_lds(
                (const __attribute__((address_space(1))) unsigned int*)gB,
                (__attribute__((address_space(3))) unsigned int*)&Bs[(r * 256 + wv * 64) * 8],
                16, 0, 0);
        }
        __syncthreads();

        short8 av[4], bv[4];
#pragma unroll
        for (int mt = 0; mt < 4; ++mt)
            av[mt] = *(const short8*)&As[(wm + mt * 16 + lr) * 32 + lq * 8];
#pragma unroll
        for (int nt = 0; nt < 4; ++nt)
            bv[nt] = *(const short8*)&Bs[(wn + nt * 16 + lr) * 32 + lq * 8];
#pragma unroll
        for (int mt = 0; mt < 4; ++mt)
#pragma unroll
            for (int nt = 0; nt < 4; ++nt)
                acc[mt][nt] = __builtin_amdgcn_mfma_f32_16x16x32_bf16(
                    av[mt], bv[nt], acc[mt][nt], 0, 0, 0);
    }

    // epilogue: D[row][col], col = lane&15, row = (lane>>4)*4 + reg
    float* Cf = (float*)Cout;
    unsigned short* Cb = (unsigned short*)Cout;
#pragma unroll
    for (int nt = 0; nt < 4; ++nt) {
        int col = bn + wn + nt * 16 + lr;
        float bv_ = bias ? bias[col] : 0.f;
#pragma unroll
        for (int mt = 0; mt < 4; ++mt) {
            int row0 = bm + wm + mt * 16 + lq * 4;
#pragma unroll
            for (int reg = 0; reg < 4; ++reg) {
                int row = row0 + reg;
                if (row >= M) continue;
                float v = acc[mt][nt][reg] + bv_;
                if (out_bf16) Cb[(size_t)row * N + col] = f2bf(v);
                else          Cf[(size_t)row * N + col] = v;
            }
        }
    }
}

// ---------------- GCN aggregation (bf16 in/out, fp32 accum) ----------------
// 256 threads = 4 waves, one node per wave (4 nodes/block) -> up to 32 waves/CU.
// Edge loop unrolled x2 with split accumulators -> 2 gathers in flight per wave.

__global__ __launch_bounds__(256) void agg_bf_k(const unsigned short* __restrict__ h,
                                                unsigned short* __restrict__ out,
                                                const float* __restrict__ bias,
                                                const float* __restrict__ dinv,
                                                const int* __restrict__ offs,
                                                const int2* __restrict__ edges,
                                                int do_relu) {
    int node = blockIdx.x * 4 + (threadIdx.x >> 6);
    if (node >= NNODES) return;
    int t = threadIdx.x & 63;            // 64 lanes x 4 ch = 256 channels
    int beg = offs[node], end = offs[node + 1];
    float a0 = 0.f, a1 = 0.f, a2 = 0.f, a3 = 0.f;
    float b0 = 0.f, b1 = 0.f, b2 = 0.f, b3 = 0.f;
    int e = beg;
    for (; e + 2 <= end; e += 2) {
        int2 ev0 = edges[e];
        int2 ev1 = edges[e + 1];
        ushort4 v0 = *(const ushort4*)(h + (size_t)ev0.x * OUTC + t * 4);
        ushort4 v1 = *(const ushort4*)(h + (size_t)ev1.x * OUTC + t * 4);
        float c0 = __int_as_float(ev0.y);
        float c1 = __int_as_float(ev1.y);
        a0 += bf2f(v0.x) * c0; a1 += bf2f(v0.y) * c0;
        a2 += bf2f(v0.z) * c0; a3 += bf2f(v0.w) * c0;
        b0 += bf2f(v1.x) * c1; b1 += bf2f(v1.y) * c1;
        b2 += bf2f(v1.z) * c1; b3 += bf2f(v1.w) * c1;
    }
    if (e < end) {
        int2 ev = edges[e];
        ushort4 v = *(const ushort4*)(h + (size_t)ev.x * OUTC + t * 4);
        float c = __int_as_float(ev.y);
        a0 += bf2f(v.x) * c; a1 += bf2f(v.y) * c;
        a2 += bf2f(v.z) * c; a3 += bf2f(v.w) * c;
    }
    a0 += b0; a1 += b1; a2 += b2; a3 += b3;
    float di = dinv[node];
    float sc = di * di;
    ushort4 hv = *(const ushort4*)(h + (size_t)node * OUTC + t * 4);
    float4 bv = *(const float4*)(bias + t * 4);
    a0 += bf2f(hv.x) * sc + bv.x;
    a1 += bf2f(hv.y) * sc + bv.y;
    a2 += bf2f(hv.z) * sc + bv.z;
    a3 += bf2f(hv.w) * sc + bv.w;
    if (do_relu) {
        a0 = fmaxf(a0, 0.f); a1 = fmaxf(a1, 0.f);
        a2 = fmaxf(a2, 0.f); a3 = fmaxf(a3, 0.f);
    }
    ushort4 u;
    u.x = f2bf(a0); u.y = f2bf(a1); u.z = f2bf(a2); u.w = f2bf(a3);
    *(ushort4*)(out + (size_t)node * OUTC + t * 4) = u;
}

// ---------------- launch ----------------

extern "C" void kernel_launch(void* const* d_in, const int* in_sizes, int n_in,
                              void* d_out, int out_size, void* d_ws, size_t ws_size,
                              hipStream_t stream) {
    const float* x    = (const float*)d_in[0];
    const int*   eidx = (const int*)d_in[1];
    const int*   midx = (const int*)d_in[2];
    const float* mtok = (const float*)d_in[3];
    const float* encW = (const float*)d_in[4];
    const float* encB = (const float*)d_in[5];
    const float* decW = (const float*)d_in[6];
    const float* decB = (const float*)d_in[7];
    const float* mlpW = (const float*)d_in[8];
    const float* mlpB = (const float*)d_in[9];
    const int* srcs = eidx;
    const int* dsts = eidx + NEDGES;

    char* ws = (char*)d_ws;
    unsigned short* x_bf  = (unsigned short*)(ws + 0);            // 51,200,000
    unsigned short* hA_bf = (unsigned short*)(ws + 51200000);     // 25,600,000 (GEMM outs)
    unsigned short* hB_bf = (unsigned short*)(ws + 76800000);     // 25,600,000 (agg outs)
    int*   deg    = (int*)  (ws + 102400000);
    float* dinv   = (float*)(ws + 102600000);
    int*   offs   = (int*)  (ws + 102800000);
    int*   cursor = (int*)  (ws + 103000064);
    int2*  edges  = (int2*) (ws + 103200064);    // 6,400,000
    float* tokh   = (float*)(ws + 109600064);    // 1,024
    unsigned short* encWt = (unsigned short*)(ws + 109601088);    // 262,144
    unsigned short* decWt = (unsigned short*)(ws + 109863232);    // 131,072
    unsigned short* mlpWt = (unsigned short*)(ws + 109994304);    // 262,144
    int*   bsum   = (int*)  (ws + 110256448);    // 256
    int*   bcarry = (int*)  (ws + 110256704);    // 256

    float* out_recon = (float*)d_out;
    float* out_x     = out_recon + (size_t)NNODES * INC;
    float* out_mask  = out_x + (size_t)NNODES * INC;

    hipMemsetAsync(deg, 0, NNODES * sizeof(int), stream);
    count_deg_k<<<(NEDGES + 255) / 256, 256, 0, stream>>>(dsts, deg);
    scan_part_k<<<NSCAN, SCAN_B, 0, stream>>>(deg, bsum, dinv);
    scan_carry_k<<<1, 64, 0, stream>>>(bsum, bcarry, offs);
    scan_fin_k<<<NSCAN, SCAN_B, 0, stream>>>(deg, bcarry, offs, cursor);
    fill_csr_k<<<(NEDGES + 255) / 256, 256, 0, stream>>>(srcs, dsts, dinv, cursor, edges,
                                                         midx, out_mask);

    token_k<<<256, 64, 0, stream>>>(mtok, encW, tokh);

    // conversions (x read once: out_x copy + bf16 cast)
    cvt_copy_k<<<(NNODES * INC / 4 + 255) / 256, 256, 0, stream>>>(
        (const float4*)x, (float4*)out_x, (ushort4*)x_bf, NNODES * INC / 4);
    wt3_k<<<(131072 + 65536 + 131072 + 255) / 256, 256, 0, stream>>>(
        encW, decW, mlpW, encWt, decWt, mlpWt);

    // encoder GEMM: h1 = x @ enc_W  (bf16 out), then mask fixup
    gemm_bf16_k<<<dim3(OUTC / 128, (NNODES + 127) / 128), 256, 0, stream>>>(
        x_bf, encWt, hA_bf, NNODES, INC, OUTC, nullptr, 1);
    maskfix_bf_k<<<NMASK, 64, 0, stream>>>(midx, tokh, hA_bf);

    // z = agg(h1) + h1*dinv^2 + enc_b  (bf16 out)
    agg_bf_k<<<(NNODES + 3) / 4, 256, 0, stream>>>(hA_bf, hB_bf, encB, dinv, offs, edges, 0);

    // decoder GEMM: h2 = z @ dec_W (bf16 out)
    gemm_bf16_k<<<dim3(DECD / 128, (NNODES + 127) / 128), 256, 0, stream>>>(
        hB_bf, decWt, hA_bf, NNODES, OUTC, DECD, nullptr, 1);

    // h = relu(agg(h2) + h2*dinv^2 + dec_b) (bf16 out)
    agg_bf_k<<<(NNODES + 3) / 4, 256, 0, stream>>>(hA_bf, hB_bf, decB, dinv, offs, edges, 1);

    // x_recon = h @ mlp_W + mlp_b -> fp32 directly to d_out
    gemm_bf16_k<<<dim3(INC / 128, (NNODES + 127) / 128), 256, 0, stream>>>(
        hB_bf, mlpWt, out_recon, NNODES, DECD, INC, mlpB, 0);
}

// Round 3
// 653.433 us; speedup vs baseline: 1.2346x; 1.0300x over previous
//
#include <hip/hip_runtime.h>
#include <math.h>

#define NNODES 50000
#define NEDGES 800000
#define INC 512
#define OUTC 256
#define DECD 256
#define NMASK 25000

#define SCAN_B 1024
#define NSCAN ((NNODES + SCAN_B - 1) / SCAN_B)   // 49 blocks

typedef __attribute__((ext_vector_type(8))) short short8;
typedef __attribute__((ext_vector_type(4))) float f32x4;

__device__ __forceinline__ unsigned short f2bf(float f) {
    unsigned int u = __float_as_uint(f);
    u = (u + 0x7fff + ((u >> 16) & 1)) >> 16;   // RNE
    return (unsigned short)u;
}
__device__ __forceinline__ float bf2f(unsigned short u) {
    return __uint_as_float(((unsigned int)u) << 16);
}

// ---------------- prep: count_deg + mask outputs/bitmap + weight transposes + token ----------------
// Block ranges:
//   [0,3125)        count_deg  (3125*256 = 800000 edges)
//   [3125,3223)     out_mask + maskbits (25088 slots >= 25000)
//   [3223,4503)     weight transposes (1280*256 = 327680 elems)
//   [4503,4567)     token_h (64 blocks x 4 j each, 64-lane reduce)
__global__ __launch_bounds__(256) void prep_k(const int* __restrict__ dst, int* __restrict__ deg,
                                              const int* __restrict__ midx,
                                              float* __restrict__ out_mask,
                                              unsigned* __restrict__ maskbits,
                                              const float* __restrict__ encW,
                                              const float* __restrict__ decW,
                                              const float* __restrict__ mlpW,
                                              unsigned short* __restrict__ encWt,
                                              unsigned short* __restrict__ decWt,
                                              unsigned short* __restrict__ mlpWt,
                                              const float* __restrict__ token,
                                              float* __restrict__ tokh) {
    int b = blockIdx.x, tid = threadIdx.x;
    if (b < 3125) {
        int e = b * 256 + tid;
        atomicAdd(&deg[dst[e]], 1);
    } else if (b < 3223) {
        int i = (b - 3125) * 256 + tid;
        if (i < NMASK) {
            int r = midx[i];
            out_mask[i] = (float)r;
            atomicOr(&maskbits[r >> 5], 1u << (r & 31));
        }
    } else if (b < 4503) {
        int o = (b - 3223) * 256 + tid;
        if (o < 131072) {                       // enc: N=256, K=512
            int n = o >> 9, k = o & 511;
            encWt[o] = f2bf(encW[(size_t)k * OUTC + n]);
        } else if (o < 196608) {                // dec: N=256, K=256
            int o2 = o - 131072;
            int n = o2 >> 8, k = o2 & 255;
            decWt[o2] = f2bf(decW[(size_t)k * DECD + n]);
        } else {                                // mlp: N=512, K=256
            int o2 = o - 196608;
            int n = o2 >> 8, k = o2 & 255;
            mlpWt[o2] = f2bf(mlpW[(size_t)k * INC + n]);
        }
    } else {
        int b2 = b - 4503;                      // 0..63
        int j = b2 * 4 + (tid >> 6);            // 0..255
        int l = tid & 63;
        float s = 0.f;
#pragma unroll
        for (int i = 0; i < INC / 64; ++i) {
            int k = i * 64 + l;
            s += token[k] * encW[(size_t)k * OUTC + j];
        }
#pragma unroll
        for (int d = 32; d > 0; d >>= 1) s += __shfl_down(s, d, 64);
        if (l == 0) tokh[j] = s;
    }
}

// ---------------- parallel scan ----------------

__global__ __launch_bounds__(1024) void scan_part_k(const int* __restrict__ deg,
                                                    int* __restrict__ bsum,
                                                    float* __restrict__ dinv) {
    int i = blockIdx.x * SCAN_B + threadIdx.x;
    int v = (i < NNODES) ? deg[i] : 0;
    if (i < NNODES) dinv[i] = rsqrtf((float)v + 1.0f);   // +1 self-loop
    int lane = threadIdx.x & 63, w = threadIdx.x >> 6;
    int s = v;
#pragma unroll
    for (int d = 32; d > 0; d >>= 1) s += __shfl_down(s, d, 64);
    __shared__ int ws[16];
    if (lane == 0) ws[w] = s;
    __syncthreads();
    if (threadIdx.x == 0) {
        int tot = 0;
#pragma unroll
        for (int j = 0; j < 16; ++j) tot += ws[j];
        bsum[blockIdx.x] = tot;
    }
}

__global__ __launch_bounds__(64) void scan_carry_k(const int* __restrict__ bsum,
                                                   int* __restrict__ bcarry,
                                                   int* __restrict__ offs) {
    int t = threadIdx.x;
    int v = (t < NSCAN) ? bsum[t] : 0;
    int incl = v;
#pragma unroll
    for (int d = 1; d < 64; d <<= 1) {
        int u = __shfl_up(incl, d, 64);
        if (t >= d) incl += u;
    }
    if (t < NSCAN) bcarry[t] = incl - v;
    if (t == 63) offs[NNODES] = incl;   // grand total (= NEDGES)
}

__global__ __launch_bounds__(1024) void scan_fin_k(const int* __restrict__ deg,
                                                   const int* __restrict__ bcarry,
                                                   int* __restrict__ offs,
                                                   int* __restrict__ cursor) {
    int i = blockIdx.x * SCAN_B + threadIdx.x;
    int v = (i < NNODES) ? deg[i] : 0;
    int lane = threadIdx.x & 63, w = threadIdx.x >> 6;
    int incl = v;
#pragma unroll
    for (int d = 1; d < 64; d <<= 1) {
        int u = __shfl_up(incl, d, 64);
        if (lane >= d) incl += u;
    }
    __shared__ int ws[16];
    if (lane == 63) ws[w] = incl;
    __syncthreads();
    int carry = bcarry[blockIdx.x];
    for (int j = 0; j < w; ++j) carry += ws[j];
    int ex = carry + incl - v;
    if (i < NNODES) { offs[i] = ex; cursor[i] = ex; }
}

// CSR fill: one 8B record per edge (src, coef).
__global__ void fill_csr_k(const int* __restrict__ src, const int* __restrict__ dst,
                           const float* __restrict__ dinv, int* __restrict__ cursor,
                           int2* __restrict__ edges) {
    int e = blockIdx.x * blockDim.x + threadIdx.x;
    if (e >= NEDGES) return;
    int s = src[e], d = dst[e];
    int pos = atomicAdd(&cursor[d], 1);
    edges[pos] = make_int2(s, __float_as_int(dinv[s] * dinv[d]));
}

// one pass over x: out_x (fp32 copy) + x_bf (bf16)
__global__ void cvt_copy_k(const float4* __restrict__ in, float4* __restrict__ outx,
                           ushort4* __restrict__ outbf, int n4) {
    int i = blockIdx.x * blockDim.x + threadIdx.x;
    if (i >= n4) return;
    float4 v = in[i];
    outx[i] = v;
    ushort4 u;
    u.x = f2bf(v.x); u.y = f2bf(v.y); u.z = f2bf(v.z); u.w = f2bf(v.w);
    outbf[i] = u;
}

// ---------------- bf16 MFMA GEMM ----------------
// C[M,N] = A[M,K](bf16) @ Bt[N,K](bf16)^T  (+bias), C fp32 or bf16.
// 128x128 tile, BK=32, 256 threads = 4 waves (2x2 of 64x64), 16x16x32 MFMA.
// Optional masked-row override: rows with maskbits set get tokh[col] (fused maskfix).

__global__ __launch_bounds__(256) void gemm_bf16_k(const unsigned short* __restrict__ A,
                                                   const unsigned short* __restrict__ Bt,
                                                   void* __restrict__ Cout,
                                                   int M, int K, int N,
                                                   const float* __restrict__ bias,
                                                   int out_bf16,
                                                   const unsigned* __restrict__ maskbits,
                                                   const float* __restrict__ tokh) {
    __shared__ unsigned short As[128 * 32];   // 8 KB
    __shared__ unsigned short Bs[128 * 32];   // 8 KB
    const int t = threadIdx.x;
    const int lane = t & 63, wv = t >> 6;
    const int bm = blockIdx.y * 128;
    const int bn = blockIdx.x * 128;
    const int wm = (wv >> 1) * 64, wn = (wv & 1) * 64;
    const int lr = lane & 15, lq = lane >> 4;

    f32x4 acc[4][4] = {};

    for (int k0 = 0; k0 < K; k0 += 32) {
        __syncthreads();
#pragma unroll
        for (int r = 0; r < 2; ++r) {
            int idx = r * 256 + wv * 64 + lane;   // 0..511
            int row = idx >> 2;                   // 0..127
            int c8 = (idx & 3) * 8;               // 0,8,16,24
            int ga = bm + row;
            if (ga >= M) ga = M - 1;              // clamp tail (stores guarded)
            const unsigned short* gA = A + (size_t)ga * K + k0 + c8;
            const unsigned short* gB = Bt + (size_t)(bn + row) * K + k0 + c8;
            __builtin_amdgcn_global_load_lds(
                (const __attribute__((address_space(1))) unsigned int*)gA,
                (__attribute__((address_space(3))) unsigned int*)&As[(r * 256 + wv * 64) * 8],
                16, 0, 0);
            __builtin_amdgcn_global_load_lds(
                (const __attribute__((address_space(1))) unsigned int*)gB,
                (__attribute__((address_space(3))) unsigned int*)&Bs[(r * 256 + wv * 64) * 8],
                16, 0, 0);
        }
        __syncthreads();

        short8 av[4], bv[4];
#pragma unroll
        for (int mt = 0; mt < 4; ++mt)
            av[mt] = *(const short8*)&As[(wm + mt * 16 + lr) * 32 + lq * 8];
#pragma unroll
        for (int nt = 0; nt < 4; ++nt)
            bv[nt] = *(const short8*)&Bs[(wn + nt * 16 + lr) * 32 + lq * 8];
#pragma unroll
        for (int mt = 0; mt < 4; ++mt)
#pragma unroll
            for (int nt = 0; nt < 4; ++nt)
                acc[mt][nt] = __builtin_amdgcn_mfma_f32_16x16x32_bf16(
                    av[mt], bv[nt], acc[mt][nt], 0, 0, 0);
    }

    // per-thread row mask bits (16 rows: mt*4+reg)
    bool mrow[16];
#pragma unroll
    for (int mt = 0; mt < 4; ++mt)
#pragma unroll
        for (int reg = 0; reg < 4; ++reg) {
            int row = bm + wm + mt * 16 + lq * 4 + reg;
            mrow[mt * 4 + reg] = false;
            if (maskbits && row < M)
                mrow[mt * 4 + reg] = (maskbits[row >> 5] >> (row & 31)) & 1;
        }

    // epilogue: D[row][col], col = lane&15, row = (lane>>4)*4 + reg
    float* Cf = (float*)Cout;
    unsigned short* Cb = (unsigned short*)Cout;
#pragma unroll
    for (int nt = 0; nt < 4; ++nt) {
        int col = bn + wn + nt * 16 + lr;
        float bv_ = bias ? bias[col] : 0.f;
        float tk = tokh ? tokh[col] : 0.f;
#pragma unroll
        for (int mt = 0; mt < 4; ++mt) {
            int row0 = bm + wm + mt * 16 + lq * 4;
#pragma unroll
            for (int reg = 0; reg < 4; ++reg) {
                int row = row0 + reg;
                if (row >= M) continue;
                float v = mrow[mt * 4 + reg] ? tk : (acc[mt][nt][reg] + bv_);
                if (out_bf16) Cb[(size_t)row * N + col] = f2bf(v);
                else          Cf[(size_t)row * N + col] = v;
            }
        }
    }
}

// ---------------- GCN aggregation (bf16 in/out, fp32 accum) ----------------
// 256 threads = 4 waves, one node per wave. Per edge: 32 lanes x 16 B (short8).
// Two edges per wave-iteration via half-waves, x2 unroll -> 4 gathers in flight.

__global__ __launch_bounds__(256) void agg_bf_k(const unsigned short* __restrict__ h,
                                                unsigned short* __restrict__ out,
                                                const float* __restrict__ bias,
                                                const float* __restrict__ dinv,
                                                const int* __restrict__ offs,
                                                const int2* __restrict__ edges,
                                                int do_relu) {
    int node = blockIdx.x * 4 + (threadIdx.x >> 6);
    if (node >= NNODES) return;
    int t = threadIdx.x & 63;
    int half = t >> 5;                 // 0: even edge, 1: odd edge
    int cb = (t & 31) * 8;             // channel base, 8 ch/lane (16 B)
    int beg = offs[node], end = offs[node + 1];
    float a[8] = {}, b[8] = {};
    int e = beg;
    for (; e + 4 <= end; e += 4) {
        int2 ev0 = edges[e + half];
        int2 ev1 = edges[e + 2 + half];
        short8 v0 = *(const short8*)(h + (size_t)ev0.x * OUTC + cb);
        short8 v1 = *(const short8*)(h + (size_t)ev1.x * OUTC + cb);
        float c0 = __int_as_float(ev0.y);
        float c1 = __int_as_float(ev1.y);
#pragma unroll
        for (int j = 0; j < 8; ++j) {
            a[j] += bf2f((unsigned short)v0[j]) * c0;
            b[j] += bf2f((unsigned short)v1[j]) * c1;
        }
    }
    if (e + 2 <= end) {
        int2 ev = edges[e + half];
        short8 v = *(const short8*)(h + (size_t)ev.x * OUTC + cb);
        float c = __int_as_float(ev.y);
#pragma unroll
        for (int j = 0; j < 8; ++j) a[j] += bf2f((unsigned short)v[j]) * c;
        e += 2;
    }
    if (e < end) {   // single leftover edge: half-1 lanes contribute 0
        int2 ev = edges[e];
        short8 v = *(const short8*)(h + (size_t)ev.x * OUTC + cb);
        float c = half ? 0.f : __int_as_float(ev.y);
#pragma unroll
        for (int j = 0; j < 8; ++j) a[j] += bf2f((unsigned short)v[j]) * c;
    }
#pragma unroll
    for (int j = 0; j < 8; ++j) {
        a[j] += b[j];
        a[j] += __shfl_xor(a[j], 32, 64);   // merge half-waves
    }
    if (half == 0) {
        float di = dinv[node];
        float sc = di * di;
        short8 hv = *(const short8*)(h + (size_t)node * OUTC + cb);
        float4 bv0 = *(const float4*)(bias + cb);
        float4 bv1 = *(const float4*)(bias + cb + 4);
        float r[8];
#pragma unroll
        for (int j = 0; j < 8; ++j) r[j] = a[j] + bf2f((unsigned short)hv[j]) * sc;
        r[0] += bv0.x; r[1] += bv0.y; r[2] += bv0.z; r[3] += bv0.w;
        r[4] += bv1.x; r[5] += bv1.y; r[6] += bv1.z; r[7] += bv1.w;
        if (do_relu) {
#pragma unroll
            for (int j = 0; j < 8; ++j) r[j] = fmaxf(r[j], 0.f);
        }
        short8 u;
#pragma unroll
        for (int j = 0; j < 8; ++j) u[j] = (short)f2bf(r[j]);
        *(short8*)(out + (size_t)node * OUTC + cb) = u;
    }
}

// ---------------- launch ----------------

extern "C" void kernel_launch(void* const* d_in, const int* in_sizes, int n_in,
                              void* d_out, int out_size, void* d_ws, size_t ws_size,
                              hipStream_t stream) {
    const float* x    = (const float*)d_in[0];
    const int*   eidx = (const int*)d_in[1];
    const int*   midx = (const int*)d_in[2];
    const float* mtok = (const float*)d_in[3];
    const float* encW = (const float*)d_in[4];
    const float* encB = (const float*)d_in[5];
    const float* decW = (const float*)d_in[6];
    const float* decB = (const float*)d_in[7];
    const float* mlpW = (const float*)d_in[8];
    const float* mlpB = (const float*)d_in[9];
    const int* srcs = eidx;
    const int* dsts = eidx + NEDGES;

    char* ws = (char*)d_ws;
    unsigned short* x_bf  = (unsigned short*)(ws + 0);              // 51,200,000
    unsigned short* hA_bf = (unsigned short*)(ws + 51200000);       // 25,600,000
    unsigned short* hB_bf = (unsigned short*)(ws + 76800000);       // 25,600,000
    int*      deg      = (int*)     (ws + 102400000);               // 200,000
    unsigned* maskbits = (unsigned*)(ws + 102600000);               // 6,400
    float*    dinv     = (float*)   (ws + 102606400);               // 200,000
    int*      offs     = (int*)     (ws + 102806400);               // 200,064
    int*      cursor   = (int*)     (ws + 103006464);               // 200,064
    int2*     edges    = (int2*)    (ws + 103206528);               // 6,400,000
    float*    tokh     = (float*)   (ws + 109606528);               // 1,024
    unsigned short* encWt = (unsigned short*)(ws + 109607552);      // 262,144
    unsigned short* decWt = (unsigned short*)(ws + 109869696);      // 131,072
    unsigned short* mlpWt = (unsigned short*)(ws + 110000768);      // 262,144
    int*      bsum     = (int*)     (ws + 110262912);               // 256
    int*      bcarry   = (int*)     (ws + 110263168);               // 256

    float* out_recon = (float*)d_out;
    float* out_x     = out_recon + (size_t)NNODES * INC;
    float* out_mask  = out_x + (size_t)NNODES * INC;

    // zero deg + maskbits in one memset (adjacent)
    hipMemsetAsync(deg, 0, 206400, stream);

    prep_k<<<4567, 256, 0, stream>>>(dsts, deg, midx, out_mask, maskbits,
                                     encW, decW, mlpW, encWt, decWt, mlpWt,
                                     mtok, tokh);

    scan_part_k<<<NSCAN, SCAN_B, 0, stream>>>(deg, bsum, dinv);
    scan_carry_k<<<1, 64, 0, stream>>>(bsum, bcarry, offs);
    scan_fin_k<<<NSCAN, SCAN_B, 0, stream>>>(deg, bcarry, offs, cursor);
    fill_csr_k<<<(NEDGES + 255) / 256, 256, 0, stream>>>(srcs, dsts, dinv, cursor, edges);

    cvt_copy_k<<<(NNODES * INC / 4 + 255) / 256, 256, 0, stream>>>(
        (const float4*)x, (float4*)out_x, (ushort4*)x_bf, NNODES * INC / 4);

    // encoder GEMM with fused mask-token epilogue: h1 = x @ enc_W (bf16 out)
    gemm_bf16_k<<<dim3(OUTC / 128, (NNODES + 127) / 128), 256, 0, stream>>>(
        x_bf, encWt, hA_bf, NNODES, INC, OUTC, nullptr, 1, maskbits, tokh);

    // z = agg(h1) + h1*dinv^2 + enc_b  (bf16 out)
    agg_bf_k<<<(NNODES + 3) / 4, 256, 0, stream>>>(hA_bf, hB_bf, encB, dinv, offs, edges, 0);

    // decoder GEMM: h2 = z @ dec_W (bf16 out)
    gemm_bf16_k<<<dim3(DECD / 128, (NNODES + 127) / 128), 256, 0, stream>>>(
        hB_bf, decWt, hA_bf, NNODES, OUTC, DECD, nullptr, 1, nullptr, nullptr);

    // h = relu(agg(h2) + h2*dinv^2 + dec_b) (bf16 out)
    agg_bf_k<<<(NNODES + 3) / 4, 256, 0, stream>>>(hA_bf, hB_bf, decB, dinv, offs, edges, 1);

    // x_recon = h @ mlp_W + mlp_b -> fp32 directly to d_out
    gemm_bf16_k<<<dim3(INC / 128, (NNODES + 127) / 128), 256, 0, stream>>>(
        hB_bf, mlpWt, out_recon, NNODES, DECD, INC, mlpB, 0, nullptr, nullptr);
}

// Round 4
// 644.926 us; speedup vs baseline: 1.2509x; 1.0132x over previous
//
#include <hip/hip_runtime.h>
#include <math.h>

#define NNODES 50000
#define NEDGES 800000
#define INC 512
#define OUTC 256
#define DECD 256
#define NMASK 25000

#define SCAN_B 1024
#define NSCAN ((NNODES + SCAN_B - 1) / SCAN_B)   // 49 blocks

// prep_k block ranges
#define PB_CVT   25000                    // 25000*256*4 floats = 25.6M elems (x)
#define PB_DEG   (PB_CVT + 3125)          // 800000 edges
#define PB_MASK  (PB_DEG + 98)            // 25088 slots
#define PB_WT    (PB_MASK + 1280)         // 327680 weight elems
#define PB_TOK   (PB_WT + 64)             // 256 j x 64 lanes

typedef __attribute__((ext_vector_type(8))) short short8;
typedef __attribute__((ext_vector_type(4))) float f32x4;

__device__ __forceinline__ unsigned short f2bf(float f) {
    unsigned int u = __float_as_uint(f);
    u = (u + 0x7fff + ((u >> 16) & 1)) >> 16;   // RNE
    return (unsigned short)u;
}
__device__ __forceinline__ float bf2f(unsigned short u) {
    return __uint_as_float(((unsigned int)u) << 16);
}

// ---------------- prep: cvt_copy + count_deg + mask + weight transposes + token ----------------

__global__ __launch_bounds__(256) void prep_k(const float4* __restrict__ x4,
                                              float4* __restrict__ outx,
                                              ushort4* __restrict__ xbf,
                                              const int* __restrict__ dst, int* __restrict__ deg,
                                              const int* __restrict__ midx,
                                              float* __restrict__ out_mask,
                                              unsigned* __restrict__ maskbits,
                                              const float* __restrict__ encW,
                                              const float* __restrict__ decW,
                                              const float* __restrict__ mlpW,
                                              unsigned short* __restrict__ encWt,
                                              unsigned short* __restrict__ decWt,
                                              unsigned short* __restrict__ mlpWt,
                                              const float* __restrict__ token,
                                              float* __restrict__ tokh) {
    int b = blockIdx.x, tid = threadIdx.x;
    if (b < PB_CVT) {
        int i = b * 256 + tid;               // < 6,400,000
        float4 v = x4[i];
        outx[i] = v;
        ushort4 u;
        u.x = f2bf(v.x); u.y = f2bf(v.y); u.z = f2bf(v.z); u.w = f2bf(v.w);
        xbf[i] = u;
    } else if (b < PB_DEG) {
        int e = (b - PB_CVT) * 256 + tid;
        atomicAdd(&deg[dst[e]], 1);
    } else if (b < PB_MASK) {
        int i = (b - PB_DEG) * 256 + tid;
        if (i < NMASK) {
            int r = midx[i];
            out_mask[i] = (float)r;
            atomicOr(&maskbits[r >> 5], 1u << (r & 31));
        }
    } else if (b < PB_WT) {
        int o = (b - PB_MASK) * 256 + tid;
        if (o < 131072) {                       // enc: N=256, K=512
            int n = o >> 9, k = o & 511;
            encWt[o] = f2bf(encW[(size_t)k * OUTC + n]);
        } else if (o < 196608) {                // dec: N=256, K=256
            int o2 = o - 131072;
            int n = o2 >> 8, k = o2 & 255;
            decWt[o2] = f2bf(decW[(size_t)k * DECD + n]);
        } else {                                // mlp: N=512, K=256
            int o2 = o - 196608;
            int n = o2 >> 8, k = o2 & 255;
            mlpWt[o2] = f2bf(mlpW[(size_t)k * INC + n]);
        }
    } else {
        int b2 = b - PB_WT;                     // 0..63
        int j = b2 * 4 + (tid >> 6);            // 0..255
        int l = tid & 63;
        float s = 0.f;
#pragma unroll
        for (int i = 0; i < INC / 64; ++i) {
            int k = i * 64 + l;
            s += token[k] * encW[(size_t)k * OUTC + j];
        }
#pragma unroll
        for (int d = 32; d > 0; d >>= 1) s += __shfl_down(s, d, 64);
        if (l == 0) tokh[j] = s;
    }
}

// ---------------- parallel scan ----------------

__global__ __launch_bounds__(1024) void scan_part_k(const int* __restrict__ deg,
                                                    int* __restrict__ bsum,
                                                    float* __restrict__ dinv) {
    int i = blockIdx.x * SCAN_B + threadIdx.x;
    int v = (i < NNODES) ? deg[i] : 0;
    if (i < NNODES) dinv[i] = rsqrtf((float)v + 1.0f);   // +1 self-loop
    int lane = threadIdx.x & 63, w = threadIdx.x >> 6;
    int s = v;
#pragma unroll
    for (int d = 32; d > 0; d >>= 1) s += __shfl_down(s, d, 64);
    __shared__ int ws[16];
    if (lane == 0) ws[w] = s;
    __syncthreads();
    if (threadIdx.x == 0) {
        int tot = 0;
#pragma unroll
        for (int j = 0; j < 16; ++j) tot += ws[j];
        bsum[blockIdx.x] = tot;
    }
}

__global__ __launch_bounds__(64) void scan_carry_k(const int* __restrict__ bsum,
                                                   int* __restrict__ bcarry,
                                                   int* __restrict__ offs) {
    int t = threadIdx.x;
    int v = (t < NSCAN) ? bsum[t] : 0;
    int incl = v;
#pragma unroll
    for (int d = 1; d < 64; d <<= 1) {
        int u = __shfl_up(incl, d, 64);
        if (t >= d) incl += u;
    }
    if (t < NSCAN) bcarry[t] = incl - v;
    if (t == 63) offs[NNODES] = incl;   // grand total (= NEDGES)
}

__global__ __launch_bounds__(1024) void scan_fin_k(const int* __restrict__ deg,
                                                   const int* __restrict__ bcarry,
                                                   int* __restrict__ offs,
                                                   int* __restrict__ cursor) {
    int i = blockIdx.x * SCAN_B + threadIdx.x;
    int v = (i < NNODES) ? deg[i] : 0;
    int lane = threadIdx.x & 63, w = threadIdx.x >> 6;
    int incl = v;
#pragma unroll
    for (int d = 1; d < 64; d <<= 1) {
        int u = __shfl_up(incl, d, 64);
        if (lane >= d) incl += u;
    }
    __shared__ int ws[16];
    if (lane == 63) ws[w] = incl;
    __syncthreads();
    int carry = bcarry[blockIdx.x];
    for (int j = 0; j < w; ++j) carry += ws[j];
    int ex = carry + incl - v;
    if (i < NNODES) { offs[i] = ex; cursor[i] = ex; }
}

// CSR fill: one 8B record per edge (src, coef).
__global__ void fill_csr_k(const int* __restrict__ src, const int* __restrict__ dst,
                           const float* __restrict__ dinv, int* __restrict__ cursor,
                           int2* __restrict__ edges) {
    int e = blockIdx.x * blockDim.x + threadIdx.x;
    if (e >= NEDGES) return;
    int s = src[e], d = dst[e];
    int pos = atomicAdd(&cursor[d], 1);
    edges[pos] = make_int2(s, __float_as_int(dinv[s] * dinv[d]));
}

// ---------------- bf16 MFMA GEMM ----------------
// C[M,N] = A[M,K](bf16) @ Bt[N,K](bf16)^T  (+bias), C fp32 or bf16.
// 128x128 tile, BK=32, 256 threads = 4 waves (2x2 of 64x64), 16x16x32 MFMA.
// Optional masked-row override: rows with maskbits set get tokh[col] (fused maskfix).

__global__ __launch_bounds__(256) void gemm_bf16_k(const unsigned short* __restrict__ A,
                                                   const unsigned short* __restrict__ Bt,
                                                   void* __restrict__ Cout,
                                                   int M, int K, int N,
                                                   const float* __restrict__ bias,
                                                   int out_bf16,
                                                   const unsigned* __restrict__ maskbits,
                                                   const float* __restrict__ tokh) {
    __shared__ unsigned short As[128 * 32];   // 8 KB
    __shared__ unsigned short Bs[128 * 32];   // 8 KB
    const int t = threadIdx.x;
    const int lane = t & 63, wv = t >> 6;
    const int bm = blockIdx.y * 128;
    const int bn = blockIdx.x * 128;
    const int wm = (wv >> 1) * 64, wn = (wv & 1) * 64;
    const int lr = lane & 15, lq = lane >> 4;

    f32x4 acc[4][4] = {};

    for (int k0 = 0; k0 < K; k0 += 32) {
        __syncthreads();
#pragma unroll
        for (int r = 0; r < 2; ++r) {
            int idx = r * 256 + wv * 64 + lane;   // 0..511
            int row = idx >> 2;                   // 0..127
            int c8 = (idx & 3) * 8;               // 0,8,16,24
            int ga = bm + row;
            if (ga >= M) ga = M - 1;              // clamp tail (stores guarded)
            const unsigned short* gA = A + (size_t)ga * K + k0 + c8;
            const unsigned short* gB = Bt + (size_t)(bn + row) * K + k0 + c8;
            __builtin_amdgcn_global_load_lds(
                (const __attribute__((address_space(1))) unsigned int*)gA,
                (__attribute__((address_space(3))) unsigned int*)&As[(r * 256 + wv * 64) * 8],
                16, 0, 0);
            __builtin_amdgcn_global_load_lds(
                (const __attribute__((address_space(1))) unsigned int*)gB,
                (__attribute__((address_space(3))) unsigned int*)&Bs[(r * 256 + wv * 64) * 8],
                16, 0, 0);
        }
        __syncthreads();

        short8 av[4], bv[4];
#pragma unroll
        for (int mt = 0; mt < 4; ++mt)
            av[mt] = *(const short8*)&As[(wm + mt * 16 + lr) * 32 + lq * 8];
#pragma unroll
        for (int nt = 0; nt < 4; ++nt)
            bv[nt] = *(const short8*)&Bs[(wn + nt * 16 + lr) * 32 + lq * 8];
#pragma unroll
        for (int mt = 0; mt < 4; ++mt)
#pragma unroll
            for (int nt = 0; nt < 4; ++nt)
                acc[mt][nt] = __builtin_amdgcn_mfma_f32_16x16x32_bf16(
                    av[mt], bv[nt], acc[mt][nt], 0, 0, 0);
    }

    // per-thread row mask bits (16 rows: mt*4+reg)
    bool mrow[16];
#pragma unroll
    for (int mt = 0; mt < 4; ++mt)
#pragma unroll
        for (int reg = 0; reg < 4; ++reg) {
            int row = bm + wm + mt * 16 + lq * 4 + reg;
            mrow[mt * 4 + reg] = false;
            if (maskbits && row < M)
                mrow[mt * 4 + reg] = (maskbits[row >> 5] >> (row & 31)) & 1;
        }

    // epilogue: D[row][col], col = lane&15, row = (lane>>4)*4 + reg
    float* Cf = (float*)Cout;
    unsigned short* Cb = (unsigned short*)Cout;
#pragma unroll
    for (int nt = 0; nt < 4; ++nt) {
        int col = bn + wn + nt * 16 + lr;
        float bv_ = bias ? bias[col] : 0.f;
        float tk = tokh ? tokh[col] : 0.f;
#pragma unroll
        for (int mt = 0; mt < 4; ++mt) {
            int row0 = bm + wm + mt * 16 + lq * 4;
#pragma unroll
            for (int reg = 0; reg < 4; ++reg) {
                int row = row0 + reg;
                if (row >= M) continue;
                float v = mrow[mt * 4 + reg] ? tk : (acc[mt][nt][reg] + bv_);
                if (out_bf16) Cb[(size_t)row * N + col] = f2bf(v);
                else          Cf[(size_t)row * N + col] = v;
            }
        }
    }
}

// ---------------- GCN aggregation (bf16 in/out, fp32 accum) ----------------
// 256 threads = 4 waves, one node per wave. Per edge: 32 lanes x 16 B (short8).
// Half-waves cover 2 edges per step; x4 unroll -> 8 gathers in flight per wave.

__global__ __launch_bounds__(256) void agg_bf_k(const unsigned short* __restrict__ h,
                                                unsigned short* __restrict__ out,
                                                const float* __restrict__ bias,
                                                const float* __restrict__ dinv,
                                                const int* __restrict__ offs,
                                                const int2* __restrict__ edges,
                                                int do_relu) {
    int node = blockIdx.x * 4 + (threadIdx.x >> 6);
    if (node >= NNODES) return;
    int t = threadIdx.x & 63;
    int half = t >> 5;                 // 0: even edge, 1: odd edge
    int cb = (t & 31) * 8;             // channel base, 8 ch/lane (16 B)
    int beg = offs[node], end = offs[node + 1];
    float a[8] = {}, b[8] = {}, c[8] = {}, d[8] = {};
    int e = beg;
    for (; e + 8 <= end; e += 8) {
        int2 ev0 = edges[e + half];
        int2 ev1 = edges[e + 2 + half];
        int2 ev2 = edges[e + 4 + half];
        int2 ev3 = edges[e + 6 + half];
        short8 v0 = *(const short8*)(h + (size_t)ev0.x * OUTC + cb);
        short8 v1 = *(const short8*)(h + (size_t)ev1.x * OUTC + cb);
        short8 v2 = *(const short8*)(h + (size_t)ev2.x * OUTC + cb);
        short8 v3 = *(const short8*)(h + (size_t)ev3.x * OUTC + cb);
        float c0 = __int_as_float(ev0.y);
        float c1 = __int_as_float(ev1.y);
        float c2 = __int_as_float(ev2.y);
        float c3 = __int_as_float(ev3.y);
#pragma unroll
        for (int j = 0; j < 8; ++j) {
            a[j] += bf2f((unsigned short)v0[j]) * c0;
            b[j] += bf2f((unsigned short)v1[j]) * c1;
            c[j] += bf2f((unsigned short)v2[j]) * c2;
            d[j] += bf2f((unsigned short)v3[j]) * c3;
        }
    }
    if (e + 4 <= end) {
        int2 ev0 = edges[e + half];
        int2 ev1 = edges[e + 2 + half];
        short8 v0 = *(const short8*)(h + (size_t)ev0.x * OUTC + cb);
        short8 v1 = *(const short8*)(h + (size_t)ev1.x * OUTC + cb);
        float c0 = __int_as_float(ev0.y);
        float c1 = __int_as_float(ev1.y);
#pragma unroll
        for (int j = 0; j < 8; ++j) {
            a[j] += bf2f((unsigned short)v0[j]) * c0;
            b[j] += bf2f((unsigned short)v1[j]) * c1;
        }
        e += 4;
    }
    if (e + 2 <= end) {
        int2 ev = edges[e + half];
        short8 v = *(const short8*)(h + (size_t)ev.x * OUTC + cb);
        float cc = __int_as_float(ev.y);
#pragma unroll
        for (int j = 0; j < 8; ++j) a[j] += bf2f((unsigned short)v[j]) * cc;
        e += 2;
    }
    if (e < end) {   // single leftover edge: half-1 lanes contribute 0
        int2 ev = edges[e];
        short8 v = *(const short8*)(h + (size_t)ev.x * OUTC + cb);
        float cc = half ? 0.f : __int_as_float(ev.y);
#pragma unroll
        for (int j = 0; j < 8; ++j) a[j] += bf2f((unsigned short)v[j]) * cc;
    }
#pragma unroll
    for (int j = 0; j < 8; ++j) {
        a[j] += b[j];
        c[j] += d[j];
        a[j] += c[j];
        a[j] += __shfl_xor(a[j], 32, 64);   // merge half-waves
    }
    if (half == 0) {
        float di = dinv[node];
        float sc = di * di;
        short8 hv = *(const short8*)(h + (size_t)node * OUTC + cb);
        float4 bv0 = *(const float4*)(bias + cb);
        float4 bv1 = *(const float4*)(bias + cb + 4);
        float r[8];
#pragma unroll
        for (int j = 0; j < 8; ++j) r[j] = a[j] + bf2f((unsigned short)hv[j]) * sc;
        r[0] += bv0.x; r[1] += bv0.y; r[2] += bv0.z; r[3] += bv0.w;
        r[4] += bv1.x; r[5] += bv1.y; r[6] += bv1.z; r[7] += bv1.w;
        if (do_relu) {
#pragma unroll
            for (int j = 0; j < 8; ++j) r[j] = fmaxf(r[j], 0.f);
        }
        short8 u;
#pragma unroll
        for (int j = 0; j < 8; ++j) u[j] = (short)f2bf(r[j]);
        *(short8*)(out + (size_t)node * OUTC + cb) = u;
    }
}

// ---------------- launch ----------------

extern "C" void kernel_launch(void* const* d_in, const int* in_sizes, int n_in,
                              void* d_out, int out_size, void* d_ws, size_t ws_size,
                              hipStream_t stream) {
    const float* x    = (const float*)d_in[0];
    const int*   eidx = (const int*)d_in[1];
    const int*   midx = (const int*)d_in[2];
    const float* mtok = (const float*)d_in[3];
    const float* encW = (const float*)d_in[4];
    const float* encB = (const float*)d_in[5];
    const float* decW = (const float*)d_in[6];
    const float* decB = (const float*)d_in[7];
    const float* mlpW = (const float*)d_in[8];
    const float* mlpB = (const float*)d_in[9];
    const int* srcs = eidx;
    const int* dsts = eidx + NEDGES;

    char* ws = (char*)d_ws;
    unsigned short* x_bf  = (unsigned short*)(ws + 0);              // 51,200,000
    unsigned short* hA_bf = (unsigned short*)(ws + 51200000);       // 25,600,000
    unsigned short* hB_bf = (unsigned short*)(ws + 76800000);       // 25,600,000
    int*      deg      = (int*)     (ws + 102400000);               // 200,000
    unsigned* maskbits = (unsigned*)(ws + 102600000);               // 6,400
    float*    dinv     = (float*)   (ws + 102606400);               // 200,000
    int*      offs     = (int*)     (ws + 102806400);               // 200,064
    int*      cursor   = (int*)     (ws + 103006464);               // 200,064
    int2*     edges    = (int2*)    (ws + 103206528);               // 6,400,000
    float*    tokh     = (float*)   (ws + 109606528);               // 1,024
    unsigned short* encWt = (unsigned short*)(ws + 109607552);      // 262,144
    unsigned short* decWt = (unsigned short*)(ws + 109869696);      // 131,072
    unsigned short* mlpWt = (unsigned short*)(ws + 110000768);      // 262,144
    int*      bsum     = (int*)     (ws + 110262912);               // 256
    int*      bcarry   = (int*)     (ws + 110263168);               // 256

    float* out_recon = (float*)d_out;
    float* out_x     = out_recon + (size_t)NNODES * INC;
    float* out_mask  = out_x + (size_t)NNODES * INC;

    // zero deg + maskbits in one memset (adjacent)
    hipMemsetAsync(deg, 0, 206400, stream);

    prep_k<<<PB_TOK, 256, 0, stream>>>((const float4*)x, (float4*)out_x, (ushort4*)x_bf,
                                       dsts, deg, midx, out_mask, maskbits,
                                       encW, decW, mlpW, encWt, decWt, mlpWt,
                                       mtok, tokh);

    scan_part_k<<<NSCAN, SCAN_B, 0, stream>>>(deg, bsum, dinv);
    scan_carry_k<<<1, 64, 0, stream>>>(bsum, bcarry, offs);
    scan_fin_k<<<NSCAN, SCAN_B, 0, stream>>>(deg, bcarry, offs, cursor);
    fill_csr_k<<<(NEDGES + 255) / 256, 256, 0, stream>>>(srcs, dsts, dinv, cursor, edges);

    // encoder GEMM with fused mask-token epilogue: h1 = x @ enc_W (bf16 out)
    gemm_bf16_k<<<dim3(OUTC / 128, (NNODES + 127) / 128), 256, 0, stream>>>(
        x_bf, encWt, hA_bf, NNODES, INC, OUTC, nullptr, 1, maskbits, tokh);

    // z = agg(h1) + h1*dinv^2 + enc_b  (bf16 out)
    agg_bf_k<<<(NNODES + 3) / 4, 256, 0, stream>>>(hA_bf, hB_bf, encB, dinv, offs, edges, 0);

    // decoder GEMM: h2 = z @ dec_W (bf16 out)
    gemm_bf16_k<<<dim3(DECD / 128, (NNODES + 127) / 128), 256, 0, stream>>>(
        hB_bf, decWt, hA_bf, NNODES, OUTC, DECD, nullptr, 1, nullptr, nullptr);

    // h = relu(agg(h2) + h2*dinv^2 + dec_b) (bf16 out)
    agg_bf_k<<<(NNODES + 3) / 4, 256, 0, stream>>>(hA_bf, hB_bf, decB, dinv, offs, edges, 1);

    // x_recon = h @ mlp_W + mlp_b -> fp32 directly to d_out
    gemm_bf16_k<<<dim3(INC / 128, (NNODES + 127) / 128), 256, 0, stream>>>(
        hB_bf, mlpWt, out_recon, NNODES, DECD, INC, mlpB, 0, nullptr, nullptr);
}

// Round 5
// 621.337 us; speedup vs baseline: 1.2984x; 1.0380x over previous
//
#include <hip/hip_runtime.h>
#include <math.h>

#define NNODES 50000
#define NEDGES 800000
#define INC 512
#define OUTC 256
#define DECD 256
#define NMASK 25000

#define SCAN_B 1024
#define NSCAN ((NNODES + SCAN_B - 1) / SCAN_B)   // 49 blocks

// prep_k block ranges
#define PB_CVT   25000                    // 25000*256*4 floats = 25.6M elems (x)
#define PB_DEG   (PB_CVT + 3125)          // 800000 edges
#define PB_MASK  (PB_DEG + 98)            // 25088 slots
#define PB_WT    (PB_MASK + 1280)         // 327680 weight elems
#define PB_TOK   (PB_WT + 64)             // 256 j x 64 lanes

// gemm1+fill merged ranges
#define G1_BLOCKS 782                     // (256/128) x ceil(50000/128) = 2 x 391
#define G1F_TOTAL (G1_BLOCKS + 3125)      // + 800000/256 fill blocks

typedef __attribute__((ext_vector_type(8))) short short8;
typedef __attribute__((ext_vector_type(4))) float f32x4;

__device__ __forceinline__ unsigned short f2bf(float f) {
    unsigned int u = __float_as_uint(f);
    u = (u + 0x7fff + ((u >> 16) & 1)) >> 16;   // RNE
    return (unsigned short)u;
}
__device__ __forceinline__ float bf2f(unsigned short u) {
    return __uint_as_float(((unsigned int)u) << 16);
}

// ---------------- prep: cvt_copy + count_deg + mask + weight transposes + token ----------------

__global__ __launch_bounds__(256) void prep_k(const float4* __restrict__ x4,
                                              float4* __restrict__ outx,
                                              ushort4* __restrict__ xbf,
                                              const int* __restrict__ dst, int* __restrict__ deg,
                                              const int* __restrict__ midx,
                                              float* __restrict__ out_mask,
                                              unsigned* __restrict__ maskbits,
                                              const float* __restrict__ encW,
                                              const float* __restrict__ decW,
                                              const float* __restrict__ mlpW,
                                              unsigned short* __restrict__ encWt,
                                              unsigned short* __restrict__ decWt,
                                              unsigned short* __restrict__ mlpWt,
                                              const float* __restrict__ token,
                                              float* __restrict__ tokh) {
    int b = blockIdx.x, tid = threadIdx.x;
    if (b < PB_CVT) {
        int i = b * 256 + tid;               // < 6,400,000
        float4 v = x4[i];
        outx[i] = v;
        ushort4 u;
        u.x = f2bf(v.x); u.y = f2bf(v.y); u.z = f2bf(v.z); u.w = f2bf(v.w);
        xbf[i] = u;
    } else if (b < PB_DEG) {
        int e = (b - PB_CVT) * 256 + tid;
        atomicAdd(&deg[dst[e]], 1);
    } else if (b < PB_MASK) {
        int i = (b - PB_DEG) * 256 + tid;
        if (i < NMASK) {
            int r = midx[i];
            out_mask[i] = (float)r;
            atomicOr(&maskbits[r >> 5], 1u << (r & 31));
        }
    } else if (b < PB_WT) {
        int o = (b - PB_MASK) * 256 + tid;
        if (o < 131072) {                       // enc: N=256, K=512
            int n = o >> 9, k = o & 511;
            encWt[o] = f2bf(encW[(size_t)k * OUTC + n]);
        } else if (o < 196608) {                // dec: N=256, K=256
            int o2 = o - 131072;
            int n = o2 >> 8, k = o2 & 255;
            decWt[o2] = f2bf(decW[(size_t)k * DECD + n]);
        } else {                                // mlp: N=512, K=256
            int o2 = o - 196608;
            int n = o2 >> 8, k = o2 & 255;
            mlpWt[o2] = f2bf(mlpW[(size_t)k * INC + n]);
        }
    } else {
        int b2 = b - PB_WT;                     // 0..63
        int j = b2 * 4 + (tid >> 6);            // 0..255
        int l = tid & 63;
        float s = 0.f;
#pragma unroll
        for (int i = 0; i < INC / 64; ++i) {
            int k = i * 64 + l;
            s += token[k] * encW[(size_t)k * OUTC + j];
        }
#pragma unroll
        for (int d = 32; d > 0; d >>= 1) s += __shfl_down(s, d, 64);
        if (l == 0) tokh[j] = s;
    }
}

// ---------------- parallel scan ----------------

__global__ __launch_bounds__(1024) void scan_part_k(const int* __restrict__ deg,
                                                    int* __restrict__ bsum,
                                                    float* __restrict__ dinv) {
    int i = blockIdx.x * SCAN_B + threadIdx.x;
    int v = (i < NNODES) ? deg[i] : 0;
    if (i < NNODES) dinv[i] = rsqrtf((float)v + 1.0f);   // +1 self-loop
    int lane = threadIdx.x & 63, w = threadIdx.x >> 6;
    int s = v;
#pragma unroll
    for (int d = 32; d > 0; d >>= 1) s += __shfl_down(s, d, 64);
    __shared__ int ws[16];
    if (lane == 0) ws[w] = s;
    __syncthreads();
    if (threadIdx.x == 0) {
        int tot = 0;
#pragma unroll
        for (int j = 0; j < 16; ++j) tot += ws[j];
        bsum[blockIdx.x] = tot;
    }
}

// scan_fin with inline carry: each block re-derives its carry from bsum[0..b).
__global__ __launch_bounds__(1024) void scan_fin_k(const int* __restrict__ deg,
                                                   const int* __restrict__ bsum,
                                                   int* __restrict__ offs,
                                                   int* __restrict__ cursor) {
    __shared__ int carry_s;
    __shared__ int ws[16];
    int tid = threadIdx.x;
    int wv = tid >> 6, lane = tid & 63;
    if (wv == 0) {
        int v = (lane < NSCAN && lane < (int)blockIdx.x) ? bsum[lane] : 0;
#pragma unroll
        for (int d = 32; d > 0; d >>= 1) v += __shfl_down(v, d, 64);
        if (lane == 0) carry_s = v;
    } else if (wv == 1 && blockIdx.x == 0) {
        int v = (lane < NSCAN) ? bsum[lane] : 0;
#pragma unroll
        for (int d = 32; d > 0; d >>= 1) v += __shfl_down(v, d, 64);
        if (lane == 0) offs[NNODES] = v;     // grand total (= NEDGES)
    }
    int i = blockIdx.x * SCAN_B + tid;
    int v = (i < NNODES) ? deg[i] : 0;
    int incl = v;
#pragma unroll
    for (int d = 1; d < 64; d <<= 1) {
        int u = __shfl_up(incl, d, 64);
        if (lane >= d) incl += u;
    }
    if (lane == 63) ws[wv] = incl;
    __syncthreads();
    int carry = carry_s;
    for (int j = 0; j < wv; ++j) carry += ws[j];
    int ex = carry + incl - v;
    if (i < NNODES) { offs[i] = ex; cursor[i] = ex; }
}

// ---------------- merged: encoder GEMM + CSR fill (independent, co-scheduled) ----------------
// blocks [0,G1_BLOCKS): h1 = x_bf @ encWt^T with fused mask-token epilogue (bf16 out)
// blocks [G1_BLOCKS,G1F_TOTAL): CSR fill (one 8B record per edge)

__global__ __launch_bounds__(256) void gemm1_fill_k(const unsigned short* __restrict__ A,
                                                    const unsigned short* __restrict__ Bt,
                                                    unsigned short* __restrict__ C,
                                                    const unsigned* __restrict__ maskbits,
                                                    const float* __restrict__ tokh,
                                                    const int* __restrict__ src,
                                                    const int* __restrict__ dst,
                                                    const float* __restrict__ dinv,
                                                    int* __restrict__ cursor,
                                                    int2* __restrict__ edges) {
    __shared__ unsigned short As[128 * 32];   // 8 KB
    __shared__ unsigned short Bs[128 * 32];   // 8 KB
    if (blockIdx.x >= G1_BLOCKS) {
        int e = (blockIdx.x - G1_BLOCKS) * 256 + threadIdx.x;
        if (e < NEDGES) {
            int s = src[e], d = dst[e];
            int pos = atomicAdd(&cursor[d], 1);
            edges[pos] = make_int2(s, __float_as_int(dinv[s] * dinv[d]));
        }
        return;
    }
    const int M = NNODES, K = INC, N = OUTC;
    const int t = threadIdx.x;
    const int lane = t & 63, wv = t >> 6;
    const int bm = (blockIdx.x >> 1) * 128;
    const int bn = (blockIdx.x & 1) * 128;
    const int wm = (wv >> 1) * 64, wn = (wv & 1) * 64;
    const int lr = lane & 15, lq = lane >> 4;

    f32x4 acc[4][4] = {};

    for (int k0 = 0; k0 < K; k0 += 32) {
        __syncthreads();
#pragma unroll
        for (int r = 0; r < 2; ++r) {
            int idx = r * 256 + wv * 64 + lane;   // 0..511
            int row = idx >> 2;                   // 0..127
            int c8 = (idx & 3) * 8;               // 0,8,16,24
            int ga = bm + row;
            if (ga >= M) ga = M - 1;              // clamp tail (stores guarded)
            const unsigned short* gA = A + (size_t)ga * K + k0 + c8;
            const unsigned short* gB = Bt + (size_t)(bn + row) * K + k0 + c8;
            __builtin_amdgcn_global_load_lds(
                (const __attribute__((address_space(1))) unsigned int*)gA,
                (__attribute__((address_space(3))) unsigned int*)&As[(r * 256 + wv * 64) * 8],
                16, 0, 0);
            __builtin_amdgcn_global_load_lds(
                (const __attribute__((address_space(1))) unsigned int*)gB,
                (__attribute__((address_space(3))) unsigned int*)&Bs[(r * 256 + wv * 64) * 8],
                16, 0, 0);
        }
        __syncthreads();

        short8 av[4], bv[4];
#pragma unroll
        for (int mt = 0; mt < 4; ++mt)
            av[mt] = *(const short8*)&As[(wm + mt * 16 + lr) * 32 + lq * 8];
#pragma unroll
        for (int nt = 0; nt < 4; ++nt)
            bv[nt] = *(const short8*)&Bs[(wn + nt * 16 + lr) * 32 + lq * 8];
#pragma unroll
        for (int mt = 0; mt < 4; ++mt)
#pragma unroll
            for (int nt = 0; nt < 4; ++nt)
                acc[mt][nt] = __builtin_amdgcn_mfma_f32_16x16x32_bf16(
                    av[mt], bv[nt], acc[mt][nt], 0, 0, 0);
    }

    bool mrow[16];
#pragma unroll
    for (int mt = 0; mt < 4; ++mt)
#pragma unroll
        for (int reg = 0; reg < 4; ++reg) {
            int row = bm + wm + mt * 16 + lq * 4 + reg;
            mrow[mt * 4 + reg] = (row < M) && ((maskbits[row >> 5] >> (row & 31)) & 1);
        }

#pragma unroll
    for (int nt = 0; nt < 4; ++nt) {
        int col = bn + wn + nt * 16 + lr;
        float tk = tokh[col];
#pragma unroll
        for (int mt = 0; mt < 4; ++mt) {
            int row0 = bm + wm + mt * 16 + lq * 4;
#pragma unroll
            for (int reg = 0; reg < 4; ++reg) {
                int row = row0 + reg;
                if (row >= M) continue;
                float v = mrow[mt * 4 + reg] ? tk : acc[mt][nt][reg];
                C[(size_t)row * N + col] = f2bf(v);
            }
        }
    }
}

// ---------------- bf16 MFMA GEMM (generic, for gemm2/gemm3) ----------------

__global__ __launch_bounds__(256) void gemm_bf16_k(const unsigned short* __restrict__ A,
                                                   const unsigned short* __restrict__ Bt,
                                                   void* __restrict__ Cout,
                                                   int M, int K, int N,
                                                   const float* __restrict__ bias,
                                                   int out_bf16) {
    __shared__ unsigned short As[128 * 32];   // 8 KB
    __shared__ unsigned short Bs[128 * 32];   // 8 KB
    const int t = threadIdx.x;
    const int lane = t & 63, wv = t >> 6;
    const int bm = blockIdx.y * 128;
    const int bn = blockIdx.x * 128;
    const int wm = (wv >> 1) * 64, wn = (wv & 1) * 64;
    const int lr = lane & 15, lq = lane >> 4;

    f32x4 acc[4][4] = {};

    for (int k0 = 0; k0 < K; k0 += 32) {
        __syncthreads();
#pragma unroll
        for (int r = 0; r < 2; ++r) {
            int idx = r * 256 + wv * 64 + lane;   // 0..511
            int row = idx >> 2;                   // 0..127
            int c8 = (idx & 3) * 8;               // 0,8,16,24
            int ga = bm + row;
            if (ga >= M) ga = M - 1;              // clamp tail (stores guarded)
            const unsigned short* gA = A + (size_t)ga * K + k0 + c8;
            const unsigned short* gB = Bt + (size_t)(bn + row) * K + k0 + c8;
            __builtin_amdgcn_global_load_lds(
                (const __attribute__((address_space(1))) unsigned int*)gA,
                (__attribute__((address_space(3))) unsigned int*)&As[(r * 256 + wv * 64) * 8],
                16, 0, 0);
            __builtin_amdgcn_global_load_lds(
                (const __attribute__((address_space(1))) unsigned int*)gB,
                (__attribute__((address_space(3))) unsigned int*)&Bs[(r * 256 + wv * 64) * 8],
                16, 0, 0);
        }
        __syncthreads();

        short8 av[4], bv[4];
#pragma unroll
        for (int mt = 0; mt < 4; ++mt)
            av[mt] = *(const short8*)&As[(wm + mt * 16 + lr) * 32 + lq * 8];
#pragma unroll
        for (int nt = 0; nt < 4; ++nt)
            bv[nt] = *(const short8*)&Bs[(wn + nt * 16 + lr) * 32 + lq * 8];
#pragma unroll
        for (int mt = 0; mt < 4; ++mt)
#pragma unroll
            for (int nt = 0; nt < 4; ++nt)
                acc[mt][nt] = __builtin_amdgcn_mfma_f32_16x16x32_bf16(
                    av[mt], bv[nt], acc[mt][nt], 0, 0, 0);
    }

    // epilogue: D[row][col], col = lane&15, row = (lane>>4)*4 + reg
    float* Cf = (float*)Cout;
    unsigned short* Cb = (unsigned short*)Cout;
#pragma unroll
    for (int nt = 0; nt < 4; ++nt) {
        int col = bn + wn + nt * 16 + lr;
        float bv_ = bias ? bias[col] : 0.f;
#pragma unroll
        for (int mt = 0; mt < 4; ++mt) {
            int row0 = bm + wm + mt * 16 + lq * 4;
#pragma unroll
            for (int reg = 0; reg < 4; ++reg) {
                int row = row0 + reg;
                if (row >= M) continue;
                float v = acc[mt][nt][reg] + bv_;
                if (out_bf16) Cb[(size_t)row * N + col] = f2bf(v);
                else          Cf[(size_t)row * N + col] = v;
            }
        }
    }
}

// ---------------- GCN aggregation (bf16 in/out, fp32 accum) ----------------
// 256 threads = 4 waves, one node per wave. Per edge: 32 lanes x 16 B (short8).
// Half-waves cover 2 edges per step; x4 unroll -> 8 gathers in flight per wave.

__global__ __launch_bounds__(256) void agg_bf_k(const unsigned short* __restrict__ h,
                                                unsigned short* __restrict__ out,
                                                const float* __restrict__ bias,
                                                const float* __restrict__ dinv,
                                                const int* __restrict__ offs,
                                                const int2* __restrict__ edges,
                                                int do_relu) {
    int node = blockIdx.x * 4 + (threadIdx.x >> 6);
    if (node >= NNODES) return;
    int t = threadIdx.x & 63;
    int half = t >> 5;                 // 0: even edge, 1: odd edge
    int cb = (t & 31) * 8;             // channel base, 8 ch/lane (16 B)
    int beg = offs[node], end = offs[node + 1];
    float a[8] = {}, b[8] = {}, c[8] = {}, d[8] = {};
    int e = beg;
    for (; e + 8 <= end; e += 8) {
        int2 ev0 = edges[e + half];
        int2 ev1 = edges[e + 2 + half];
        int2 ev2 = edges[e + 4 + half];
        int2 ev3 = edges[e + 6 + half];
        short8 v0 = *(const short8*)(h + (size_t)ev0.x * OUTC + cb);
        short8 v1 = *(const short8*)(h + (size_t)ev1.x * OUTC + cb);
        short8 v2 = *(const short8*)(h + (size_t)ev2.x * OUTC + cb);
        short8 v3 = *(const short8*)(h + (size_t)ev3.x * OUTC + cb);
        float c0 = __int_as_float(ev0.y);
        float c1 = __int_as_float(ev1.y);
        float c2 = __int_as_float(ev2.y);
        float c3 = __int_as_float(ev3.y);
#pragma unroll
        for (int j = 0; j < 8; ++j) {
            a[j] += bf2f((unsigned short)v0[j]) * c0;
            b[j] += bf2f((unsigned short)v1[j]) * c1;
            c[j] += bf2f((unsigned short)v2[j]) * c2;
            d[j] += bf2f((unsigned short)v3[j]) * c3;
        }
    }
    if (e + 4 <= end) {
        int2 ev0 = edges[e + half];
        int2 ev1 = edges[e + 2 + half];
        short8 v0 = *(const short8*)(h + (size_t)ev0.x * OUTC + cb);
        short8 v1 = *(const short8*)(h + (size_t)ev1.x * OUTC + cb);
        float c0 = __int_as_float(ev0.y);
        float c1 = __int_as_float(ev1.y);
#pragma unroll
        for (int j = 0; j < 8; ++j) {
            a[j] += bf2f((unsigned short)v0[j]) * c0;
            b[j] += bf2f((unsigned short)v1[j]) * c1;
        }
        e += 4;
    }
    if (e + 2 <= end) {
        int2 ev = edges[e + half];
        short8 v = *(const short8*)(h + (size_t)ev.x * OUTC + cb);
        float cc = __int_as_float(ev.y);
#pragma unroll
        for (int j = 0; j < 8; ++j) a[j] += bf2f((unsigned short)v[j]) * cc;
        e += 2;
    }
    if (e < end) {   // single leftover edge: half-1 lanes contribute 0
        int2 ev = edges[e];
        short8 v = *(const short8*)(h + (size_t)ev.x * OUTC + cb);
        float cc = half ? 0.f : __int_as_float(ev.y);
#pragma unroll
        for (int j = 0; j < 8; ++j) a[j] += bf2f((unsigned short)v[j]) * cc;
    }
#pragma unroll
    for (int j = 0; j < 8; ++j) {
        a[j] += b[j];
        c[j] += d[j];
        a[j] += c[j];
        a[j] += __shfl_xor(a[j], 32, 64);   // merge half-waves
    }
    if (half == 0) {
        float di = dinv[node];
        float sc = di * di;
        short8 hv = *(const short8*)(h + (size_t)node * OUTC + cb);
        float4 bv0 = *(const float4*)(bias + cb);
        float4 bv1 = *(const float4*)(bias + cb + 4);
        float r[8];
#pragma unroll
        for (int j = 0; j < 8; ++j) r[j] = a[j] + bf2f((unsigned short)hv[j]) * sc;
        r[0] += bv0.x; r[1] += bv0.y; r[2] += bv0.z; r[3] += bv0.w;
        r[4] += bv1.x; r[5] += bv1.y; r[6] += bv1.z; r[7] += bv1.w;
        if (do_relu) {
#pragma unroll
            for (int j = 0; j < 8; ++j) r[j] = fmaxf(r[j], 0.f);
        }
        short8 u;
#pragma unroll
        for (int j = 0; j < 8; ++j) u[j] = (short)f2bf(r[j]);
        *(short8*)(out + (size_t)node * OUTC + cb) = u;
    }
}

// ---------------- launch ----------------

extern "C" void kernel_launch(void* const* d_in, const int* in_sizes, int n_in,
                              void* d_out, int out_size, void* d_ws, size_t ws_size,
                              hipStream_t stream) {
    const float* x    = (const float*)d_in[0];
    const int*   eidx = (const int*)d_in[1];
    const int*   midx = (const int*)d_in[2];
    const float* mtok = (const float*)d_in[3];
    const float* encW = (const float*)d_in[4];
    const float* encB = (const float*)d_in[5];
    const float* decW = (const float*)d_in[6];
    const float* decB = (const float*)d_in[7];
    const float* mlpW = (const float*)d_in[8];
    const float* mlpB = (const float*)d_in[9];
    const int* srcs = eidx;
    const int* dsts = eidx + NEDGES;

    char* ws = (char*)d_ws;
    unsigned short* x_bf  = (unsigned short*)(ws + 0);              // 51,200,000
    unsigned short* hA_bf = (unsigned short*)(ws + 51200000);       // 25,600,000
    unsigned short* hB_bf = (unsigned short*)(ws + 76800000);       // 25,600,000
    int*      deg      = (int*)     (ws + 102400000);               // 200,000
    unsigned* maskbits = (unsigned*)(ws + 102600000);               // 6,400
    float*    dinv     = (float*)   (ws + 102606400);               // 200,000
    int*      offs     = (int*)     (ws + 102806400);               // 200,064
    int*      cursor   = (int*)     (ws + 103006464);               // 200,064
    int2*     edges    = (int2*)    (ws + 103206528);               // 6,400,000
    float*    tokh     = (float*)   (ws + 109606528);               // 1,024
    unsigned short* encWt = (unsigned short*)(ws + 109607552);      // 262,144
    unsigned short* decWt = (unsigned short*)(ws + 109869696);      // 131,072
    unsigned short* mlpWt = (unsigned short*)(ws + 110000768);      // 262,144
    int*      bsum     = (int*)     (ws + 110262912);               // 256

    float* out_recon = (float*)d_out;
    float* out_x     = out_recon + (size_t)NNODES * INC;
    float* out_mask  = out_x + (size_t)NNODES * INC;

    // zero deg + maskbits in one memset (adjacent)
    hipMemsetAsync(deg, 0, 206400, stream);

    prep_k<<<PB_TOK, 256, 0, stream>>>((const float4*)x, (float4*)out_x, (ushort4*)x_bf,
                                       dsts, deg, midx, out_mask, maskbits,
                                       encW, decW, mlpW, encWt, decWt, mlpWt,
                                       mtok, tokh);

    scan_part_k<<<NSCAN, SCAN_B, 0, stream>>>(deg, bsum, dinv);
    scan_fin_k<<<NSCAN, SCAN_B, 0, stream>>>(deg, bsum, offs, cursor);

    // merged: encoder GEMM (h1 = x @ enc_W, fused mask-token) + CSR fill
    gemm1_fill_k<<<G1F_TOTAL, 256, 0, stream>>>(x_bf, encWt, hA_bf, maskbits, tokh,
                                                srcs, dsts, dinv, cursor, edges);

    // z = agg(h1) + h1*dinv^2 + enc_b  (bf16 out)
    agg_bf_k<<<(NNODES + 3) / 4, 256, 0, stream>>>(hA_bf, hB_bf, encB, dinv, offs, edges, 0);

    // decoder GEMM: h2 = z @ dec_W (bf16 out)
    gemm_bf16_k<<<dim3(DECD / 128, (NNODES + 127) / 128), 256, 0, stream>>>(
        hB_bf, decWt, hA_bf, NNODES, OUTC, DECD, nullptr, 1);

    // h = relu(agg(h2) + h2*dinv^2 + dec_b) (bf16 out)
    agg_bf_k<<<(NNODES + 3) / 4, 256, 0, stream>>>(hA_bf, hB_bf, decB, dinv, offs, edges, 1);

    // x_recon = h @ mlp_W + mlp_b -> fp32 directly to d_out
    gemm_bf16_k<<<dim3(INC / 128, (NNODES + 127) / 128), 256, 0, stream>>>(
        hB_bf, mlpWt, out_recon, NNODES, DECD, INC, mlpB, 0);
}